// Round 17
// baseline (331.179 us; speedup 1.0000x reference)
//
#include <hip/hip_runtime.h>

typedef unsigned short u16;
typedef unsigned int   u32;
typedef __attribute__((ext_vector_type(8))) short bf16x8;
typedef __attribute__((ext_vector_type(4))) float f32x4;

#define B_      8
#define HW_     112
#define C_      192
#define NH_     6
#define HD_     32
#define L_      (HW_*HW_)       // 12544
#define M_      (B_*L_)         // 100352
#define MLP_    768
#define QKVN_   576
#define LOG100_ 4.6051702f
#define LOG2E_  1.44269504f

__device__ __forceinline__ float bf2f(u16 u){
  union { float f; u32 i; } v; v.i = ((u32)u) << 16; return v.f;
}
__device__ __forceinline__ u16 f2bf(float f){
  union { float f; u32 i; } v; v.f = f;
  u32 r = (v.i + 0x7fffu + ((v.i >> 16) & 1u)) >> 16;
  return (u16)r;
}
// hardware packed f32->bf16 (RNE)
__device__ __forceinline__ u32 cvtpk(float a, float b){
  u32 r;
  asm("v_cvt_pk_bf16_f32 %0, %1, %2" : "=v"(r) : "v"(a), "v"(b));
  return r;
}
__device__ __forceinline__ void u4_to_f8(uint4 u, float* f){
  f[0]=bf2f((u16)(u.x&0xffffu)); f[1]=bf2f((u16)(u.x>>16));
  f[2]=bf2f((u16)(u.y&0xffffu)); f[3]=bf2f((u16)(u.y>>16));
  f[4]=bf2f((u16)(u.z&0xffffu)); f[5]=bf2f((u16)(u.z>>16));
  f[6]=bf2f((u16)(u.w&0xffffu)); f[7]=bf2f((u16)(u.w>>16));
}

// local window index t (0..48) -> token row (elements) with reverse cyclic shift
__device__ __forceinline__ int rowelem(int b, int wh, int ww, int t){
  int i = t/7, j = t - i*7;
  int oi = wh*7 + i + 3; if (oi >= 112) oi -= 112;
  int oj = ww*7 + j + 3; if (oj >= 112) oj -= 112;
  return b*L_ + oi*112 + oj;
}

// ---------------- weight prep: transpose to [N][K] bf16, biases f32 ----------
__global__ __launch_bounds__(256) void prep_weights(
    const float* __restrict__ qw, const float* __restrict__ qb,
    const float* __restrict__ kw, const float* __restrict__ vw,
    const float* __restrict__ vb, const float* __restrict__ pw,
    const float* __restrict__ pb, const float* __restrict__ f1w,
    const float* __restrict__ f1b, const float* __restrict__ f2w,
    const float* __restrict__ f2b,
    u16* __restrict__ wt_qkv, float* __restrict__ b_qkv,
    u16* __restrict__ wt_p,   float* __restrict__ b_p,
    u16* __restrict__ wt_f1,  float* __restrict__ b_f1,
    u16* __restrict__ wt_f2,  float* __restrict__ b_f2)
{
  const int S1 = 110592, S2 = 147456, S3 = 294912, S4 = 442368, TOT = 444096;
  int i = blockIdx.x*256 + threadIdx.x;
  if (i >= TOT) return;
  if (i < S1) {                       // wt_qkv[576][192]
    int n = i/192, k = i%192;
    float v = (n<192) ? qw[k*192+n] : ((n<384) ? kw[k*192+(n-192)] : vw[k*192+(n-384)]);
    wt_qkv[i] = f2bf(v);
  } else if (i < S2) {                // wt_p[192][192]
    int j = i - S1; int n = j/192, k = j%192;
    wt_p[j] = f2bf(pw[k*192+n]);
  } else if (i < S3) {                // wt_f1[768][192]
    int j = i - S2; int n = j/192, k = j%192;
    wt_f1[j] = f2bf(f1w[k*768+n]);
  } else if (i < S4) {                // wt_f2[192][768]
    int j = i - S3; int n = j/768, k = j%768;
    wt_f2[j] = f2bf(f2w[k*192+n]);
  } else {
    int j = i - S4;
    if (j < 576)        b_qkv[j] = (j<192) ? qb[j] : ((j<384) ? 0.f : vb[j-384]);
    else if (j < 768)   b_p[j-576]   = pb[j-576];
    else if (j < 1536)  b_f1[j-768]  = f1b[j-768];
    else                b_f2[j-1536] = f2b[j-1536];
  }
}

// ---------------- relative position bias ------------------------------------
__device__ __forceinline__ float reltab(float x){
  float v = x * (8.f/6.f);
  float r = __log2f(fabsf(v) + 1.f) * (1.f/3.f);
  return (v < 0.f) ? -r : r;
}

__global__ __launch_bounds__(64) void rpb_a_kernel(
    const float* __restrict__ w0, const float* __restrict__ b0,
    const float* __restrict__ w1, float* __restrict__ rpb169)
{
  int tt = blockIdx.x, lane = threadIdx.x;
  float t0 = reltab((float)(tt/13 - 6));
  float t1 = reltab((float)(tt%13 - 6));
  float acc[6] = {0.f,0.f,0.f,0.f,0.f,0.f};
  for (int j = lane; j < 512; j += 64){
    float hid = fmaxf(t0*w0[j] + t1*w0[512+j] + b0[j], 0.f);
#pragma unroll
    for (int h=0; h<6; h++) acc[h] += hid * w1[j*6+h];
  }
#pragma unroll
  for (int h=0; h<6; h++){
#pragma unroll
    for (int m=32; m>=1; m>>=1) acc[h] += __shfl_xor(acc[h], m);
  }
  if (lane == 0){
#pragma unroll
    for (int h=0; h<6; h++) rpb169[tt*6+h] = acc[h];
  }
}

// biasQ[type][head][q(64)][slot(64)] with slot j -> actual key via sigma:
// kt=j>>4, s=j&15, key = (kt>=2)*32 + (s>>2)*8 + (kt&1)*4 + (s&3)
__global__ __launch_bounds__(256) void rpb_b_kernel(
    const float* __restrict__ rpb169, float* __restrict__ biasQ)
{
  int i = blockIdx.x*256 + threadIdx.x;   // 4*6*64*64 = 98304
  if (i >= 98304) return;
  int j = i & 63, q = (i >> 6) & 63;
  int rest = i >> 12;                      // 0..23
  int hh = rest % 6, type = rest / 6;
  int kt = j >> 4, s = j & 15;
  int key = ((kt>>1)<<5) + ((s>>2)<<3) + ((kt&1)<<2) + (s&3);
  float val;
  if (key >= 49) val = -60000.f;
  else if (q >= 49) val = 0.f;
  else {
    int qi = q/7, qj = q%7, ki = key/7, kj = key%7;
    int idx = (qi - ki + 6)*13 + (qj - kj + 6);
    float x = rpb169[idx*6 + hh];
    float sig = 16.f / (1.f + __expf(-x));
    int th = type >> 1, tw = type & 1;
    int rq = (th ? (qi<4?1:2) : 0)*3 + (tw ? (qj<4?1:2) : 0);
    int rk = (th ? (ki<4?1:2) : 0)*3 + (tw ? (kj<4?1:2) : 0);
    float msk = (rq != rk) ? -100.f : 0.f;
    val = (sig + msk) * LOG2E_;
  }
  biasQ[i] = val;
}

// ======================= GEMM common ========================================
__device__ __forceinline__ float fast_gelu(float v){
  float t = v*v;
  float w = v * fmaf(-0.1029432f, t, -2.30220817f);   // -2u*log2(e)
  float e = exp2f(w);
  return v * __builtin_amdgcn_rcpf(1.f + e);
}

#define MODE_GELU 0
#define MODE_LN1  1   // out16 = f2bf(base32 + LN(v))
#define MODE_LN2  2   // out32 = bf2f(base16) + LN(v)

// tile 128x192, BK=32, 512 thr = 8 waves of 32x96, 2-phase LDS (syncthreads).
// NOTE: (512,4) only — (512,8) caps VGPR at 64 and spills acc to scratch (R11).
template<int K, int MODE>
__global__ __launch_bounds__(512,4) void gemm_fused(
    const u16* __restrict__ A, const u16* __restrict__ Wt,
    const float* __restrict__ bias,
    const float* __restrict__ lng, const float* __restrict__ lnb,
    const float* __restrict__ base32, const u16* __restrict__ base16,
    u16* __restrict__ out16, float* __restrict__ out32, int NN)
{
  __shared__ __align__(16) u16 lds[20480];
  const int tid  = threadIdx.x;
  const int wave = tid >> 6, lane = tid & 63;
  const int m0 = blockIdx.x * 128;
  const int n0 = blockIdx.y * 192;
  const int wr = wave >> 1, wc = wave & 1;     // wave tile 32 x 96
  const int lrow = lane >> 2, lslot = lane & 3;
  const int gk = (lslot ^ ((lrow >> 1) & 3)) * 8;

  const u16* gsrc[3]; u32 ldst[3]; const int nst = (wave < 4) ? 3 : 2;
#pragma unroll
  for (int t=0; t<3; t++){
    int c = wave + t*8;
    if (c < 8)       { gsrc[t] = A  + (size_t)(m0 + c*16 + lrow)*K + gk;      ldst[t] = (u32)(c*512); }
    else if (c < 20) { gsrc[t] = Wt + (size_t)(n0 + (c-8)*16 + lrow)*K + gk;  ldst[t] = (u32)(4096 + (c-8)*512); }
    else             { gsrc[t] = A; ldst[t] = 0; }
  }
  const int lr16 = lane & 15;
  const int lg   = lane >> 4;
  const int slot8 = (lg ^ ((lr16 >> 1) & 3)) * 8;
  u32 aoff[2], boff[6];
#pragma unroll
  for (int mt=0; mt<2; mt++) aoff[mt] = (u32)((wr*32 + mt*16 + lr16)*32 + slot8);
#pragma unroll
  for (int nt=0; nt<6; nt++) boff[nt] = (u32)(4096 + (wc*96 + nt*16 + lr16)*32 + slot8);

  f32x4 acc[2][6];
#pragma unroll
  for (int mt=0; mt<2; mt++)
#pragma unroll
    for (int nt=0; nt<6; nt++)
      acc[mt][nt] = (f32x4){0.f,0.f,0.f,0.f};

  const int NT = K/32;
#define STAGE_F(tt, ph) do { \
  _Pragma("unroll") \
  for (int s_=0; s_<3; s_++) if (s_ < nst) \
    __builtin_amdgcn_global_load_lds( \
        (const __attribute__((address_space(1))) void*)(gsrc[s_] + (tt)*32), \
        (__attribute__((address_space(3))) void*)&lds[ldst[s_] + (ph)], 16, 0, 0); \
} while(0)

  STAGE_F(0, 0u);
  __syncthreads();
  for (int t=0; t<NT; t++){
    const u32 pb = (u32)(t&1)*10240u;
    if (t+1 < NT) STAGE_F(t+1, pb ^ 10240u);
    bf16x8 af[2], bf[6];
#pragma unroll
    for (int mt=0; mt<2; mt++) af[mt] = *(const bf16x8*)&lds[pb + aoff[mt]];
#pragma unroll
    for (int nt=0; nt<6; nt++) bf[nt] = *(const bf16x8*)&lds[pb + boff[nt]];
#pragma unroll
    for (int mt=0; mt<2; mt++)
#pragma unroll
      for (int nt=0; nt<6; nt++)
        acc[mt][nt] = __builtin_amdgcn_mfma_f32_16x16x32_bf16(af[mt], bf[nt], acc[mt][nt], 0, 0, 0);
    __syncthreads();
  }
#undef STAGE_F

#pragma unroll
  for (int nt=0; nt<6; nt++){
    float bsv = bias[n0 + wc*96 + nt*16 + lr16];
#pragma unroll
    for (int mt=0; mt<2; mt++)
#pragma unroll
      for (int r2=0; r2<4; r2++) acc[mt][nt][r2] += bsv;
  }

  if (MODE == MODE_GELU){
#pragma unroll
    for (int mt=0; mt<2; mt++){
      int rbase = m0 + wr*32 + mt*16 + lg*4;
#pragma unroll
      for (int nt=0; nt<6; nt++){
        int col = n0 + wc*96 + nt*16 + lr16;
#pragma unroll
        for (int r2=0; r2<4; r2++)
          out16[(size_t)(rbase + r2)*NN + col] = f2bf(fast_gelu(acc[mt][nt][r2]));
      }
    }
  } else {
    float sv[2][4], sq[2][4];
#pragma unroll
    for (int mt=0; mt<2; mt++)
#pragma unroll
      for (int r2=0; r2<4; r2++){
        float s=0.f, q=0.f;
#pragma unroll
        for (int nt=0; nt<6; nt++){ float x = acc[mt][nt][r2]; s += x; q += x*x; }
        sv[mt][r2]=s; sq[mt][r2]=q;
      }
#pragma unroll
    for (int d=1; d<16; d<<=1){
#pragma unroll
      for (int mt=0; mt<2; mt++)
#pragma unroll
        for (int r2=0; r2<4; r2++){
          sv[mt][r2] += __shfl_xor(sv[mt][r2], d);
          sq[mt][r2] += __shfl_xor(sq[mt][r2], d);
        }
    }
    float* red = (float*)lds;   // 128 rows x {svc0,sqc0,svc1,sqc1}
    if (lr16 == 0){
#pragma unroll
      for (int mt=0; mt<2; mt++)
#pragma unroll
        for (int r2=0; r2<4; r2++){
          int row = wr*32 + mt*16 + lg*4 + r2;
          red[row*4 + wc*2]     = sv[mt][r2];
          red[row*4 + wc*2 + 1] = sq[mt][r2];
        }
    }
    __syncthreads();
    float mean[2][4], rstd[2][4];
#pragma unroll
    for (int mt=0; mt<2; mt++)
#pragma unroll
      for (int r2=0; r2<4; r2++){
        int row = wr*32 + mt*16 + lg*4 + r2;
        float s = red[row*4] + red[row*4+2];
        float q = red[row*4+1] + red[row*4+3];
        float m = s*(1.f/192.f);
        float v = fmaxf(q*(1.f/192.f) - m*m, 0.f);
        mean[mt][r2] = m; rstd[mt][r2] = rsqrtf(v + 1e-5f);
      }
    float gg[6], be[6];
#pragma unroll
    for (int nt=0; nt<6; nt++){
      int col = n0 + wc*96 + nt*16 + lr16;
      gg[nt] = lng[col]; be[nt] = lnb[col];
    }
#pragma unroll
    for (int mt=0; mt<2; mt++){
      int rbase = m0 + wr*32 + mt*16 + lg*4;
#pragma unroll
      for (int nt=0; nt<6; nt++){
        int col = n0 + wc*96 + nt*16 + lr16;
#pragma unroll
        for (int r2=0; r2<4; r2++){
          size_t idx = (size_t)(rbase + r2)*192 + col;
          float r = (acc[mt][nt][r2] - mean[mt][r2])*rstd[mt][r2]*gg[nt] + be[nt];
          if (MODE == MODE_LN1){
            r += base32[idx];
            out16[idx] = f2bf(r);
          } else {
            r += bf2f(base16[idx]);
            out32[idx] = r;
          }
        }
      }
    }
  }
}

// ---- QKV GEMM v2: tile 64x192 (4704 blocks), A f32 reg-staged ---------------
__global__ __launch_bounds__(512,4) void gemm_qkv_kernel(
    const float* __restrict__ X, const u16* __restrict__ Wt,
    const float* __restrict__ bias, u16* __restrict__ out)
{
  __shared__ __align__(16) u16 lds[16384];   // phase: A [0,2048) B [2048,8192); stride 8192
  const int tid  = threadIdx.x;
  const int wave = tid >> 6, lane = tid & 63;
  const int m0 = blockIdx.x * 64;
  const int n0 = blockIdx.y * 192;
  const int wr = wave >> 1, wc = wave & 1;   // wave tile 16 x 96
  const int lrow = lane >> 2, lslot = lane & 3;
  const int gk = (lslot ^ ((lrow >> 1) & 3)) * 8;

  const u16* gsrcB[2]; u32 ldstB[2]; const int nstB = (wave < 4) ? 2 : 1;
#pragma unroll
  for (int t=0; t<2; t++){
    int c = wave + t*8;
    if (c < 12) { gsrcB[t] = Wt + (size_t)(n0 + c*16 + lrow)*192 + gk; ldstB[t] = (u32)(2048 + c*512); }
    else        { gsrcB[t] = Wt; ldstB[t] = 2048; }
  }
  const int ar = tid >> 3, aq = tid & 7;
  const float* gA = X + (size_t)(m0 + ar)*192 + aq*4;
  const u32 dsta = (u32)(ar*32 + ((aq>>1) ^ ((ar>>1)&3))*8 + (aq&1)*4);

  const int lr16 = lane & 15;
  const int lg   = lane >> 4;
  const int slot8 = (lg ^ ((lr16 >> 1) & 3)) * 8;
  const u32 aoff = (u32)((wr*16 + lr16)*32 + slot8);
  u32 boff[6];
#pragma unroll
  for (int nt=0; nt<6; nt++) boff[nt] = (u32)(2048 + (wc*96 + nt*16 + lr16)*32 + slot8);

  f32x4 acc[6];
#pragma unroll
  for (int nt=0; nt<6; nt++) acc[nt] = (f32x4){0.f,0.f,0.f,0.f};

#define STAGE_B(tt, ph) do { \
  _Pragma("unroll") \
  for (int s_=0; s_<2; s_++) if (s_ < nstB) \
    __builtin_amdgcn_global_load_lds( \
        (const __attribute__((address_space(1))) void*)(gsrcB[s_] + (tt)*32), \
        (__attribute__((address_space(3))) void*)&lds[ldstB[s_] + (ph)], 16, 0, 0); \
} while(0)

  {
    float4 a0 = *(const float4*)gA;
    STAGE_B(0, 0u);
    uint2 aw;
    aw.x = cvtpk(a0.x, a0.y); aw.y = cvtpk(a0.z, a0.w);
    *(uint2*)(void*)&lds[dsta] = aw;
  }
  __syncthreads();

  for (int t=0; t<6; t++){
    const u32 pb = (u32)(t&1)*8192u;
    const u32 pn = pb ^ 8192u;
    float4 a0;
    if (t < 5){
      a0 = *(const float4*)(gA + (t+1)*32);
      STAGE_B(t+1, pn);
    }
    bf16x8 af = *(const bf16x8*)&lds[pb + aoff];
    bf16x8 bf[6];
#pragma unroll
    for (int nt=0; nt<6; nt++) bf[nt] = *(const bf16x8*)&lds[pb + boff[nt]];
#pragma unroll
    for (int nt=0; nt<6; nt++)
      acc[nt] = __builtin_amdgcn_mfma_f32_16x16x32_bf16(af, bf[nt], acc[nt], 0, 0, 0);
    if (t < 5){
      uint2 aw;
      aw.x = cvtpk(a0.x, a0.y); aw.y = cvtpk(a0.z, a0.w);
      *(uint2*)(void*)&lds[pn + dsta] = aw;
    }
    __syncthreads();
  }
#undef STAGE_B

  {
    int rbase = m0 + wr*16 + lg*4;
#pragma unroll
    for (int nt=0; nt<6; nt++){
      int col = n0 + wc*96 + nt*16 + lr16;
      float bsv = bias[col];
#pragma unroll
      for (int r2=0; r2<4; r2++)
        out[(size_t)(rbase + r2)*QKVN_ + col] = f2bf(acc[nt][r2] + bsv);
    }
  }
}

// ------- windowed cosine attention, all-register P, 6 heads per block --------
__global__ __launch_bounds__(384) void attn_kernel(
    const u16* __restrict__ qkv, const float* __restrict__ lsc,
    const float* __restrict__ biasQ, u16* __restrict__ attn_out)
{
  __shared__ __align__(16) u16 smem[12288];  // 6 x 4KB head regions
  const int tid  = threadIdx.x;
  const int wave = tid >> 6;
  const int lane = tid & 63;
  char* smb = (char*)smem + wave*4096;
  const int hh = wave;
  const int w  = blockIdx.x;
  const int b  = w >> 8;
  const int wh = (w >> 4) & 15, ww = w & 15;
  const int lg = lane >> 4, lr = lane & 15;
  const int type = ((wh==15)?2:0) + ((ww==15)?1:0);
  const float qscale = __expf(fminf(lsc[hh], LOG100_)) * LOG2E_;

  union BU { bf16x8 v; u32 u[4]; };

  const int myrow = rowelem(b, wh, ww, min(lane, 48));

  const u16* vsrc = qkv + (size_t)myrow*QKVN_ + 384 + hh*32;
  uint4 vld[4];
#pragma unroll
  for (int r=0; r<4; r++) vld[r] = *(const uint4*)(vsrc + r*8);

  int rowq[4], krow[4];
#pragma unroll
  for (int qt=0; qt<4; qt++) rowq[qt] = __shfl(myrow, qt*16 + lr);
#pragma unroll
  for (int kt=0; kt<4; kt++){
    int sig = ((kt>>1)<<5) + ((lr>>2)<<3) + ((kt&1)<<2) + (lr&3);
    krow[kt] = __shfl(myrow, sig);
  }

  bf16x8 qf[4], kf[4];
#pragma unroll
  for (int qt=0; qt<4; qt++){
    const u16* base = qkv + (size_t)rowq[qt]*QKVN_ + hh*32 + lg*8;
    uint4 u = *(const uint4*)base;
    float f[8]; u4_to_f8(u, f);
    float ss = 0.f;
#pragma unroll
    for (int d=0; d<8; d++) ss += f[d]*f[d];
    ss += __shfl_xor(ss, 16); ss += __shfl_xor(ss, 32);
    float rn = qscale * __builtin_amdgcn_rcpf(fmaxf(sqrtf(ss), 1e-6f));
    BU bu;
#pragma unroll
    for (int p=0; p<4; p++) bu.u[p] = cvtpk(f[2*p]*rn, f[2*p+1]*rn);
    qf[qt] = bu.v;
  }
#pragma unroll
  for (int kt=0; kt<4; kt++){
    const u16* base = qkv + (size_t)krow[kt]*QKVN_ + 192 + hh*32 + lg*8;
    uint4 u = *(const uint4*)base;
    float f[8]; u4_to_f8(u, f);
    float ss = 0.f;
#pragma unroll
    for (int d=0; d<8; d++) ss += f[d]*f[d];
    ss += __shfl_xor(ss, 16); ss += __shfl_xor(ss, 32);
    float rn = __builtin_amdgcn_rcpf(fmaxf(sqrtf(ss), 1e-6f));
    BU bu;
#pragma unroll
    for (int p=0; p<4; p++) bu.u[p] = cvtpk(f[2*p]*rn, f[2*p+1]*rn);
    kf[kt] = bu.v;
  }

  f32x4 s2[4][4];
#pragma unroll
  for (int kt=0; kt<4; kt++)
#pragma unroll
    for (int qt=0; qt<4; qt++)
      s2[kt][qt] = __builtin_amdgcn_mfma_f32_16x16x32_bf16(kf[kt], qf[qt],
                     (f32x4){0.f,0.f,0.f,0.f}, 0, 0, 0);

#pragma unroll
  for (int r=0; r<4; r++){
    u32 wds[4] = {vld[r].x, vld[r].y, vld[r].z, vld[r].w};
#pragma unroll
    for (int i=0; i<8; i++){
      int d = r*8 + i;
      u16 val = (u16)(wds[i>>1] >> ((i&1)*16));
      int addr = (d*128 + lane*2) ^ ((d&7)<<4);
      *(u16*)(smb + addr) = val;
    }
  }

  const float* bq = biasQ + (size_t)(type*6 + hh)*4096;
#pragma unroll
  for (int qt=0; qt<4; qt++){
    int q = qt*16 + lr;
#pragma unroll
    for (int kt=0; kt<4; kt++){
      f32x4 bv = *(const f32x4*)(bq + q*64 + kt*16 + lg*4);
      s2[kt][qt] += bv;
    }
  }
#pragma unroll
  for (int qt=0; qt<4; qt++){
    float m = s2[0][qt][0];
#pragma unroll
    for (int kt=0; kt<4; kt++)
#pragma unroll
      for (int r2=0; r2<4; r2++) m = fmaxf(m, s2[kt][qt][r2]);
    m = fmaxf(m, __shfl_xor(m, 16));
    m = fmaxf(m, __shfl_xor(m, 32));
    float sum = 0.f;
#pragma unroll
    for (int kt=0; kt<4; kt++)
#pragma unroll
      for (int r2=0; r2<4; r2++){
        float e = exp2f(s2[kt][qt][r2] - m);
        s2[kt][qt][r2] = e; sum += e;
      }
    sum += __shfl_xor(sum, 16);
    sum += __shfl_xor(sum, 32);
    float rs = __builtin_amdgcn_rcpf(sum);
#pragma unroll
    for (int kt=0; kt<4; kt++)
#pragma unroll
      for (int r2=0; r2<4; r2++) s2[kt][qt][r2] *= rs;
  }

  __syncthreads();   // V^T ready

  f32x4 o2[2][4];
#pragma unroll
  for (int dt=0; dt<2; dt++)
#pragma unroll
    for (int qt=0; qt<4; qt++)
      o2[dt][qt] = (f32x4){0.f,0.f,0.f,0.f};

#pragma unroll
  for (int kb=0; kb<2; kb++){
    bf16x8 af[2];
#pragma unroll
    for (int dt=0; dt<2; dt++){
      int d = dt*16 + lr;
      int addr = (d*128 + kb*64 + lg*16) ^ ((d&7)<<4);
      af[dt] = *(const bf16x8*)(smb + addr);
    }
#pragma unroll
    for (int qt=0; qt<4; qt++){
      BU bu;
      bu.u[0] = cvtpk(s2[2*kb][qt][0],   s2[2*kb][qt][1]);
      bu.u[1] = cvtpk(s2[2*kb][qt][2],   s2[2*kb][qt][3]);
      bu.u[2] = cvtpk(s2[2*kb+1][qt][0], s2[2*kb+1][qt][1]);
      bu.u[3] = cvtpk(s2[2*kb+1][qt][2], s2[2*kb+1][qt][3]);
#pragma unroll
      for (int dt=0; dt<2; dt++)
        o2[dt][qt] = __builtin_amdgcn_mfma_f32_16x16x32_bf16(af[dt], bu.v, o2[dt][qt], 0, 0, 0);
    }
  }

#pragma unroll
  for (int qt=0; qt<4; qt++){
    int q = qt*16 + lr;
    if (q < 49){
      u16* op = attn_out + (size_t)rowq[qt]*C_ + hh*32;
#pragma unroll
      for (int dt=0; dt<2; dt++){
        uint2 u2;
        u2.x = cvtpk(o2[dt][qt][0], o2[dt][qt][1]);
        u2.y = cvtpk(o2[dt][qt][2], o2[dt][qt][3]);
        *(uint2*)(void*)(op + dt*16 + lg*4) = u2;
      }
    }
  }
}

// --------- fused MLP v5: A in registers, LDS = mid + B only (50KB) ----------
// 64 rows/block, 512 thr = 8 waves of 16x96; 3 blocks/CU.
__global__ __launch_bounds__(512,4) void mlp_fused_kernel(
    const u16* __restrict__ h1,           // [M][192] bf16
    const u16* __restrict__ wf1,          // [768][192] bf16
    const float* __restrict__ bf1,        // [768]
    const u16* __restrict__ wf2,          // [192][768] bf16
    const float* __restrict__ bf2,        // [192]
    const float* __restrict__ lng, const float* __restrict__ lnb,
    float* __restrict__ out)              // [M][192] f32
{
  // LDS: mid [0,25600) 64x200 bf16 | B ph0 [25600,37888) | B ph1 [37888,50176)
  //      | red [50176,51200)
  __shared__ __align__(16) char smb[51200];
  const int tid  = threadIdx.x;
  const int wave = tid >> 6, lane = tid & 63;
  const int m0 = blockIdx.x * 64;
  const int wr = wave >> 1, wc = wave & 1;     // wave tile 16 rows x 96 cols
  const int lr16 = lane & 15, lg = lane >> 4;
  const int lrow = lane >> 2, lslot = lane & 3;
  const int gko = (lslot ^ ((lrow >> 1) & 3)) * 8;
  const int slot8 = (lg ^ ((lr16 >> 1) & 3)) * 8;

  // A fragments in registers: row = m0 + wr*16 + lr16, k-slot lg*8 (+k*32)
  const u16* arow = h1 + (size_t)(m0 + wr*16 + lr16)*192 + lg*8;
  bf16x8 afr[6];
#pragma unroll
  for (int k=0; k<6; k++) afr[k] = *(const bf16x8*)(arow + k*32);

  // B staging bases (hoisted; offsets constant after c-unroll)
  const u16* w1b[2]; const u16* w2b[2]; u32 ldb[2];
  const int nstB = (wave < 4) ? 2 : 1;
#pragma unroll
  for (int s=0; s<2; s++){
    int ch = wave + s*8;
    if (ch < 12){
      w1b[s] = wf1 + (size_t)(ch*16 + lrow)*192 + gko;
      w2b[s] = wf2 + (size_t)(ch*16 + lrow)*768 + gko;
      ldb[s] = (u32)(ch*1024);
    } else { w1b[s] = wf1; w2b[s] = wf2; ldb[s] = 0; }
  }

#define STG1(c_, k_, ph_) do { \
  _Pragma("unroll") \
  for (int s_=0; s_<2; s_++) if (s_ < nstB) \
    __builtin_amdgcn_global_load_lds( \
        (const __attribute__((address_space(1))) void*)(w1b[s_] + (c_)*36864 + (k_)*32), \
        (__attribute__((address_space(3))) void*)(smb + (ph_) + ldb[s_]), 16, 0, 0); \
} while(0)
#define STG2(c_, k_, ph_) do { \
  _Pragma("unroll") \
  for (int s_=0; s_<2; s_++) if (s_ < nstB) \
    __builtin_amdgcn_global_load_lds( \
        (const __attribute__((address_space(1))) void*)(w2b[s_] + (c_)*192 + (k_)*32), \
        (__attribute__((address_space(3))) void*)(smb + (ph_) + ldb[s_]), 16, 0, 0); \
} while(0)

  f32x4 oacc[6];
#pragma unroll
  for (int nt=0; nt<6; nt++) oacc[nt] = (f32x4){0.f,0.f,0.f,0.f};

#pragma unroll
  for (int c=0; c<4; c++){
    // ---------- fc1 chunk: macc = A(reg) @ wf1_c^T ---------------------------
    f32x4 macc[6];
#pragma unroll
    for (int nt=0; nt<6; nt++) macc[nt] = (f32x4){0.f,0.f,0.f,0.f};

    STG1(c, 0, 25600u);
    __syncthreads();
#pragma unroll
    for (int k=0; k<6; k++){
      u32 pb = 25600u + (u32)(k&1)*12288u;
      if (k < 5) STG1(c, k+1, 25600u + (u32)((k+1)&1)*12288u);
      bf16x8 bfv[6];
#pragma unroll
      for (int nt=0; nt<6; nt++)
        bfv[nt] = *(const bf16x8*)(smb + pb + ((wc*96 + nt*16 + lr16)*32 + slot8)*2);
#pragma unroll
      for (int nt=0; nt<6; nt++)
        macc[nt] = __builtin_amdgcn_mfma_f32_16x16x32_bf16(afr[k], bfv[nt], macc[nt], 0, 0, 0);
      __syncthreads();
    }
    // issue fc2 B tile 0 before gelu (latency hides under VALU)
    STG2(c, 0, 25600u);
    // gelu + write mid
#pragma unroll
    for (int nt=0; nt<6; nt++){
      int col = wc*96 + nt*16 + lr16;
      float bsv = bf1[c*192 + col];
#pragma unroll
      for (int r2=0; r2<4; r2++){
        int tok = wr*16 + lg*4 + r2;
        float g = fast_gelu(macc[nt][r2] + bsv);
        *(u16*)(smb + (tok*200 + col)*2) = f2bf(g);
      }
    }
    __syncthreads();   // mid ready + B tile 0
    // ---------- fc2 chunk: oacc += mid @ wf2_cslice^T ------------------------
#pragma unroll
    for (int k=0; k<6; k++){
      u32 pb = 25600u + (u32)(k&1)*12288u;
      if (k < 5) STG2(c, k+1, 25600u + (u32)((k+1)&1)*12288u);
      bf16x8 af = *(const bf16x8*)(smb + ((wr*16 + lr16)*200 + k*32 + lg*8)*2);
      bf16x8 bfv[6];
#pragma unroll
      for (int nt=0; nt<6; nt++)
        bfv[nt] = *(const bf16x8*)(smb + pb + ((wc*96 + nt*16 + lr16)*32 + slot8)*2);
#pragma unroll
      for (int nt=0; nt<6; nt++)
        oacc[nt] = __builtin_amdgcn_mfma_f32_16x16x32_bf16(af, bfv[nt], oacc[nt], 0, 0, 0);
      __syncthreads();
    }
  }
#undef STG1
#undef STG2

  // ---------- epilogue: bias + LN2 + residual (h1 from L2) -> f32 out --------
#pragma unroll
  for (int nt=0; nt<6; nt++){
    float bsv = bf2[wc*96 + nt*16 + lr16];
#pragma unroll
    for (int r2=0; r2<4; r2++) oacc[nt][r2] += bsv;
  }
  float sv[4], sq[4];
#pragma unroll
  for (int r2=0; r2<4; r2++){
    float s=0.f, q=0.f;
#pragma unroll
    for (int nt=0; nt<6; nt++){ float x = oacc[nt][r2]; s += x; q += x*x; }
    sv[r2]=s; sq[r2]=q;
  }
#pragma unroll
  for (int d=1; d<16; d<<=1){
#pragma unroll
    for (int r2=0; r2<4; r2++){
      sv[r2] += __shfl_xor(sv[r2], d);
      sq[r2] += __shfl_xor(sq[r2], d);
    }
  }
  float* red = (float*)(smb + 50176);
  if (lr16 == 0){
#pragma unroll
    for (int r2=0; r2<4; r2++){
      int row = wr*16 + lg*4 + r2;
      red[row*4 + wc*2]     = sv[r2];
      red[row*4 + wc*2 + 1] = sq[r2];
    }
  }
  __syncthreads();
  float gg[6], be[6];
#pragma unroll
  for (int nt=0; nt<6; nt++){
    int col = wc*96 + nt*16 + lr16;
    gg[nt] = lng[col]; be[nt] = lnb[col];
  }
#pragma unroll
  for (int r2=0; r2<4; r2++){
    int row = wr*16 + lg*4 + r2;
    float s = red[row*4] + red[row*4+2];
    float q = red[row*4+1] + red[row*4+3];
    float mean = s*(1.f/192.f);
    float var  = fmaxf(q*(1.f/192.f) - mean*mean, 0.f);
    float rstd = rsqrtf(var + 1e-5f);
#pragma unroll
    for (int nt=0; nt<6; nt++){
      int col = wc*96 + nt*16 + lr16;
      float base = bf2f(h1[(size_t)(m0 + row)*192 + col]);
      out[(size_t)(m0 + row)*192 + col] = base + (oacc[nt][r2] - mean)*rstd*gg[nt] + be[nt];
    }
  }
}

// ---------------- launch ------------------------------------------------------
extern "C" void kernel_launch(void* const* d_in, const int* in_sizes, int n_in,
                              void* d_out, int out_size, void* d_ws, size_t ws_size,
                              hipStream_t stream)
{
  (void)in_sizes; (void)n_in; (void)out_size; (void)ws_size;
  const float* x      = (const float*)d_in[0];
  const float* q_w    = (const float*)d_in[1];
  const float* q_b    = (const float*)d_in[2];
  const float* k_w    = (const float*)d_in[3];
  const float* v_w    = (const float*)d_in[4];
  const float* v_b    = (const float*)d_in[5];
  const float* proj_w = (const float*)d_in[6];
  const float* proj_b = (const float*)d_in[7];
  const float* lsc    = (const float*)d_in[8];
  const float* cpb_w0 = (const float*)d_in[9];
  const float* cpb_b0 = (const float*)d_in[10];
  const float* cpb_w1 = (const float*)d_in[11];
  const float* ln1_g  = (const float*)d_in[12];
  const float* ln1_b  = (const float*)d_in[13];
  const float* ln2_g  = (const float*)d_in[14];
  const float* ln2_b  = (const float*)d_in[15];
  const float* fc1_w  = (const float*)d_in[16];
  const float* fc1_b  = (const float*)d_in[17];
  const float* fc2_w  = (const float*)d_in[18];
  const float* fc2_b  = (const float*)d_in[19];

  char* ws = (char*)d_ws;
  size_t o = 0;
  u16* qkvb = (u16*)(ws + o);    o += 154140672;
  u16* attn_o = (u16*)(ws + o);
  u16* h1b    = attn_o;          o += 38535168;    // attn_o -> h1b (in-place fused)
  u16* wt_qkv = (u16*)(ws + o);  o += 221184;
  float* b_qkv= (float*)(ws + o);o += 2304;
  u16* wt_p   = (u16*)(ws + o);  o += 73728;
  float* b_p  = (float*)(ws + o);o += 768;
  u16* wt_f1  = (u16*)(ws + o);  o += 294912;
  float* b_f1 = (float*)(ws + o);o += 3072;
  u16* wt_f2  = (u16*)(ws + o);  o += 294912;
  float* b_f2 = (float*)(ws + o);o += 768;
  float* rpb169 = (float*)(ws + o); o += 4096;
  float* biasQ  = (float*)(ws + o); o += 393216;

  prep_weights<<<1735, 256, 0, stream>>>(q_w, q_b, k_w, v_w, v_b, proj_w, proj_b,
      fc1_w, fc1_b, fc2_w, fc2_b, wt_qkv, b_qkv, wt_p, b_p, wt_f1, b_f1, wt_f2, b_f2);
  rpb_a_kernel<<<169, 64, 0, stream>>>(cpb_w0, cpb_b0, cpb_w1, rpb169);
  rpb_b_kernel<<<384, 256, 0, stream>>>(rpb169, biasQ);

  gemm_qkv_kernel<<<dim3(1568,3), 512, 0, stream>>>(x, wt_qkv, b_qkv, qkvb);
  attn_kernel<<<2048, 384, 0, stream>>>(qkvb, lsc, biasQ, attn_o);
  // h1b = x + LN1(attn_o @ wp + bp)
  gemm_fused<192, MODE_LN1><<<dim3(784,1), 512, 0, stream>>>(
      attn_o, wt_p, b_p, ln1_g, ln1_b, x, nullptr, h1b, nullptr, 192);
  // out = h1b + LN2(gelu(h1b@wf1+b1)@wf2+b2)
  mlp_fused_kernel<<<1568, 512, 0, stream>>>(
      h1b, wt_f1, b_f1, wt_f2, b_f2, ln2_g, ln2_b, (float*)d_out);
}

// Round 18
// 295.627 us; speedup vs baseline: 1.1203x; 1.1203x over previous
//
#include <hip/hip_runtime.h>

typedef unsigned short u16;
typedef unsigned int   u32;
typedef __attribute__((ext_vector_type(8))) short bf16x8;
typedef __attribute__((ext_vector_type(4))) float f32x4;

#define B_      8
#define HW_     112
#define C_      192
#define NH_     6
#define HD_     32
#define L_      (HW_*HW_)       // 12544
#define M_      (B_*L_)         // 100352
#define MLP_    768
#define QKVN_   576
#define LOG100_ 4.6051702f
#define LOG2E_  1.44269504f

__device__ __forceinline__ float bf2f(u16 u){
  union { float f; u32 i; } v; v.i = ((u32)u) << 16; return v.f;
}
__device__ __forceinline__ u16 f2bf(float f){
  union { float f; u32 i; } v; v.f = f;
  u32 r = (v.i + 0x7fffu + ((v.i >> 16) & 1u)) >> 16;
  return (u16)r;
}
// hardware packed f32->bf16 (RNE)
__device__ __forceinline__ u32 cvtpk(float a, float b){
  u32 r;
  asm("v_cvt_pk_bf16_f32 %0, %1, %2" : "=v"(r) : "v"(a), "v"(b));
  return r;
}
__device__ __forceinline__ void u4_to_f8(uint4 u, float* f){
  f[0]=bf2f((u16)(u.x&0xffffu)); f[1]=bf2f((u16)(u.x>>16));
  f[2]=bf2f((u16)(u.y&0xffffu)); f[3]=bf2f((u16)(u.y>>16));
  f[4]=bf2f((u16)(u.z&0xffffu)); f[5]=bf2f((u16)(u.z>>16));
  f[6]=bf2f((u16)(u.w&0xffffu)); f[7]=bf2f((u16)(u.w>>16));
}

// local window index t (0..48) -> token row (elements) with reverse cyclic shift
__device__ __forceinline__ int rowelem(int b, int wh, int ww, int t){
  int i = t/7, j = t - i*7;
  int oi = wh*7 + i + 3; if (oi >= 112) oi -= 112;
  int oj = ww*7 + j + 3; if (oj >= 112) oj -= 112;
  return b*L_ + oi*112 + oj;
}

// ---------------- weight prep: transpose to [N][K] bf16, biases f32 ----------
__global__ __launch_bounds__(256) void prep_weights(
    const float* __restrict__ qw, const float* __restrict__ qb,
    const float* __restrict__ kw, const float* __restrict__ vw,
    const float* __restrict__ vb, const float* __restrict__ pw,
    const float* __restrict__ pb, const float* __restrict__ f1w,
    const float* __restrict__ f1b, const float* __restrict__ f2w,
    const float* __restrict__ f2b,
    u16* __restrict__ wt_qkv, float* __restrict__ b_qkv,
    u16* __restrict__ wt_p,   float* __restrict__ b_p,
    u16* __restrict__ wt_f1,  float* __restrict__ b_f1,
    u16* __restrict__ wt_f2,  float* __restrict__ b_f2)
{
  const int S1 = 110592, S2 = 147456, S3 = 294912, S4 = 442368, TOT = 444096;
  int i = blockIdx.x*256 + threadIdx.x;
  if (i >= TOT) return;
  if (i < S1) {                       // wt_qkv[576][192]
    int n = i/192, k = i%192;
    float v = (n<192) ? qw[k*192+n] : ((n<384) ? kw[k*192+(n-192)] : vw[k*192+(n-384)]);
    wt_qkv[i] = f2bf(v);
  } else if (i < S2) {                // wt_p[192][192]
    int j = i - S1; int n = j/192, k = j%192;
    wt_p[j] = f2bf(pw[k*192+n]);
  } else if (i < S3) {                // wt_f1[768][192]
    int j = i - S2; int n = j/192, k = j%192;
    wt_f1[j] = f2bf(f1w[k*768+n]);
  } else if (i < S4) {                // wt_f2[192][768]
    int j = i - S3; int n = j/768, k = j%768;
    wt_f2[j] = f2bf(f2w[k*192+n]);
  } else {
    int j = i - S4;
    if (j < 576)        b_qkv[j] = (j<192) ? qb[j] : ((j<384) ? 0.f : vb[j-384]);
    else if (j < 768)   b_p[j-576]   = pb[j-576];
    else if (j < 1536)  b_f1[j-768]  = f1b[j-768];
    else                b_f2[j-1536] = f2b[j-1536];
  }
}

// ---------------- relative position bias ------------------------------------
__device__ __forceinline__ float reltab(float x){
  float v = x * (8.f/6.f);
  float r = __log2f(fabsf(v) + 1.f) * (1.f/3.f);
  return (v < 0.f) ? -r : r;
}

__global__ __launch_bounds__(64) void rpb_a_kernel(
    const float* __restrict__ w0, const float* __restrict__ b0,
    const float* __restrict__ w1, float* __restrict__ rpb169)
{
  int tt = blockIdx.x, lane = threadIdx.x;
  float t0 = reltab((float)(tt/13 - 6));
  float t1 = reltab((float)(tt%13 - 6));
  float acc[6] = {0.f,0.f,0.f,0.f,0.f,0.f};
  for (int j = lane; j < 512; j += 64){
    float hid = fmaxf(t0*w0[j] + t1*w0[512+j] + b0[j], 0.f);
#pragma unroll
    for (int h=0; h<6; h++) acc[h] += hid * w1[j*6+h];
  }
#pragma unroll
  for (int h=0; h<6; h++){
#pragma unroll
    for (int m=32; m>=1; m>>=1) acc[h] += __shfl_xor(acc[h], m);
  }
  if (lane == 0){
#pragma unroll
    for (int h=0; h<6; h++) rpb169[tt*6+h] = acc[h];
  }
}

// biasQ[type][head][q(64)][slot(64)] with slot j -> actual key via sigma:
// kt=j>>4, s=j&15, key = (kt>=2)*32 + (s>>2)*8 + (kt&1)*4 + (s&3)
__global__ __launch_bounds__(256) void rpb_b_kernel(
    const float* __restrict__ rpb169, float* __restrict__ biasQ)
{
  int i = blockIdx.x*256 + threadIdx.x;   // 4*6*64*64 = 98304
  if (i >= 98304) return;
  int j = i & 63, q = (i >> 6) & 63;
  int rest = i >> 12;                      // 0..23
  int hh = rest % 6, type = rest / 6;
  int kt = j >> 4, s = j & 15;
  int key = ((kt>>1)<<5) + ((s>>2)<<3) + ((kt&1)<<2) + (s&3);
  float val;
  if (key >= 49) val = -60000.f;
  else if (q >= 49) val = 0.f;
  else {
    int qi = q/7, qj = q%7, ki = key/7, kj = key%7;
    int idx = (qi - ki + 6)*13 + (qj - kj + 6);
    float x = rpb169[idx*6 + hh];
    float sig = 16.f / (1.f + __expf(-x));
    int th = type >> 1, tw = type & 1;
    int rq = (th ? (qi<4?1:2) : 0)*3 + (tw ? (qj<4?1:2) : 0);
    int rk = (th ? (ki<4?1:2) : 0)*3 + (tw ? (kj<4?1:2) : 0);
    float msk = (rq != rk) ? -100.f : 0.f;
    val = (sig + msk) * LOG2E_;
  }
  biasQ[i] = val;
}

// ======================= common =============================================
__device__ __forceinline__ float fast_gelu(float v){
  float t = v*v;
  float w = v * fmaf(-0.1029432f, t, -2.30220817f);   // -2u*log2(e)
  float e = exp2f(w);
  return v * __builtin_amdgcn_rcpf(1.f + e);
}

// ---- QKV GEMM v2: tile 64x192 (4704 blocks), A f32 reg-staged ---------------
__global__ __launch_bounds__(512,4) void gemm_qkv_kernel(
    const float* __restrict__ X, const u16* __restrict__ Wt,
    const float* __restrict__ bias, u16* __restrict__ out)
{
  __shared__ __align__(16) u16 lds[16384];   // phase: A [0,2048) B [2048,8192); stride 8192
  const int tid  = threadIdx.x;
  const int wave = tid >> 6, lane = tid & 63;
  const int m0 = blockIdx.x * 64;
  const int n0 = blockIdx.y * 192;
  const int wr = wave >> 1, wc = wave & 1;   // wave tile 16 x 96
  const int lrow = lane >> 2, lslot = lane & 3;
  const int gk = (lslot ^ ((lrow >> 1) & 3)) * 8;

  const u16* gsrcB[2]; u32 ldstB[2]; const int nstB = (wave < 4) ? 2 : 1;
#pragma unroll
  for (int t=0; t<2; t++){
    int c = wave + t*8;
    if (c < 12) { gsrcB[t] = Wt + (size_t)(n0 + c*16 + lrow)*192 + gk; ldstB[t] = (u32)(2048 + c*512); }
    else        { gsrcB[t] = Wt; ldstB[t] = 2048; }
  }
  const int ar = tid >> 3, aq = tid & 7;
  const float* gA = X + (size_t)(m0 + ar)*192 + aq*4;
  const u32 dsta = (u32)(ar*32 + ((aq>>1) ^ ((ar>>1)&3))*8 + (aq&1)*4);

  const int lr16 = lane & 15;
  const int lg   = lane >> 4;
  const int slot8 = (lg ^ ((lr16 >> 1) & 3)) * 8;
  const u32 aoff = (u32)((wr*16 + lr16)*32 + slot8);
  u32 boff[6];
#pragma unroll
  for (int nt=0; nt<6; nt++) boff[nt] = (u32)(2048 + (wc*96 + nt*16 + lr16)*32 + slot8);

  f32x4 acc[6];
#pragma unroll
  for (int nt=0; nt<6; nt++) acc[nt] = (f32x4){0.f,0.f,0.f,0.f};

#define STAGE_B(tt, ph) do { \
  _Pragma("unroll") \
  for (int s_=0; s_<2; s_++) if (s_ < nstB) \
    __builtin_amdgcn_global_load_lds( \
        (const __attribute__((address_space(1))) void*)(gsrcB[s_] + (tt)*32), \
        (__attribute__((address_space(3))) void*)&lds[ldstB[s_] + (ph)], 16, 0, 0); \
} while(0)

  {
    float4 a0 = *(const float4*)gA;
    STAGE_B(0, 0u);
    uint2 aw;
    aw.x = cvtpk(a0.x, a0.y); aw.y = cvtpk(a0.z, a0.w);
    *(uint2*)(void*)&lds[dsta] = aw;
  }
  __syncthreads();

  for (int t=0; t<6; t++){
    const u32 pb = (u32)(t&1)*8192u;
    const u32 pn = pb ^ 8192u;
    float4 a0;
    if (t < 5){
      a0 = *(const float4*)(gA + (t+1)*32);
      STAGE_B(t+1, pn);
    }
    bf16x8 af = *(const bf16x8*)&lds[pb + aoff];
    bf16x8 bf[6];
#pragma unroll
    for (int nt=0; nt<6; nt++) bf[nt] = *(const bf16x8*)&lds[pb + boff[nt]];
#pragma unroll
    for (int nt=0; nt<6; nt++)
      acc[nt] = __builtin_amdgcn_mfma_f32_16x16x32_bf16(af, bf[nt], acc[nt], 0, 0, 0);
    if (t < 5){
      uint2 aw;
      aw.x = cvtpk(a0.x, a0.y); aw.y = cvtpk(a0.z, a0.w);
      *(uint2*)(void*)&lds[pn + dsta] = aw;
    }
    __syncthreads();
  }
#undef STAGE_B

  {
    int rbase = m0 + wr*16 + lg*4;
#pragma unroll
    for (int nt=0; nt<6; nt++){
      int col = n0 + wc*96 + nt*16 + lr16;
      float bsv = bias[col];
#pragma unroll
      for (int r2=0; r2<4; r2++)
        out[(size_t)(rbase + r2)*QKVN_ + col] = f2bf(acc[nt][r2] + bsv);
    }
  }
}

// ---- proj+LN1 v2: tile 64x192 (1568 blocks), A bf16 via global_load_lds -----
// h1b = x + LN1(attn_o @ Wp + bp).  In-place safe: block reads only rows it
// writes; all A reads drain before the epilogue stores.
__global__ __launch_bounds__(512,4) void proj_ln1_kernel(
    const u16* __restrict__ A, const u16* __restrict__ Wt,
    const float* __restrict__ bias,
    const float* __restrict__ lng, const float* __restrict__ lnb,
    const float* __restrict__ base32, u16* __restrict__ out16)
{
  // bytes: phase0 [0,16384) phase1 [16384,32768) | red [32768,33792)
  __shared__ __align__(16) char smb[33792];
  u16* lds = (u16*)smb;
  const int tid  = threadIdx.x;
  const int wave = tid >> 6, lane = tid & 63;
  const int m0 = blockIdx.x * 64;
  const int wr = wave >> 1, wc = wave & 1;   // wave tile 16 x 96
  const int lrow = lane >> 2, lslot = lane & 3;
  const int gk = (lslot ^ ((lrow >> 1) & 3)) * 8;

  // 16 chunks of 1KB: c<4 -> A rows c*16.., else B rows (c-4)*16..
  const u16* gsrc[2]; u32 ldst[2];
#pragma unroll
  for (int t=0; t<2; t++){
    int c = wave + t*8;
    if (c < 4) { gsrc[t] = A  + (size_t)(m0 + c*16 + lrow)*192 + gk;   ldst[t] = (u32)(c*512); }
    else       { gsrc[t] = Wt + (size_t)((c-4)*16 + lrow)*192 + gk;    ldst[t] = (u32)(2048 + (c-4)*512); }
  }
  const int lr16 = lane & 15;
  const int lg   = lane >> 4;
  const int slot8 = (lg ^ ((lr16 >> 1) & 3)) * 8;
  const u32 aoff = (u32)((wr*16 + lr16)*32 + slot8);
  u32 boff[6];
#pragma unroll
  for (int nt=0; nt<6; nt++) boff[nt] = (u32)(2048 + (wc*96 + nt*16 + lr16)*32 + slot8);

  f32x4 acc[6];
#pragma unroll
  for (int nt=0; nt<6; nt++) acc[nt] = (f32x4){0.f,0.f,0.f,0.f};

#define STAGE_P(tt, ph) do { \
  _Pragma("unroll") \
  for (int s_=0; s_<2; s_++) \
    __builtin_amdgcn_global_load_lds( \
        (const __attribute__((address_space(1))) void*)(gsrc[s_] + (tt)*32), \
        (__attribute__((address_space(3))) void*)&lds[ldst[s_] + (ph)], 16, 0, 0); \
} while(0)

  STAGE_P(0, 0u);
  __syncthreads();
  for (int t=0; t<6; t++){
    const u32 pb = (u32)(t&1)*8192u;
    if (t < 5) STAGE_P(t+1, pb ^ 8192u);
    bf16x8 af = *(const bf16x8*)&lds[pb + aoff];
    bf16x8 bf[6];
#pragma unroll
    for (int nt=0; nt<6; nt++) bf[nt] = *(const bf16x8*)&lds[pb + boff[nt]];
#pragma unroll
    for (int nt=0; nt<6; nt++)
      acc[nt] = __builtin_amdgcn_mfma_f32_16x16x32_bf16(af, bf[nt], acc[nt], 0, 0, 0);
    __syncthreads();
  }
#undef STAGE_P

  // bias (pre-LN value)
#pragma unroll
  for (int nt=0; nt<6; nt++){
    float bsv = bias[wc*96 + nt*16 + lr16];
#pragma unroll
    for (int r2=0; r2<4; r2++) acc[nt][r2] += bsv;
  }
  // per-row LN over 192 cols (two wc halves)
  float sv[4], sq[4];
#pragma unroll
  for (int r2=0; r2<4; r2++){
    float s=0.f, q=0.f;
#pragma unroll
    for (int nt=0; nt<6; nt++){ float x = acc[nt][r2]; s += x; q += x*x; }
    sv[r2]=s; sq[r2]=q;
  }
#pragma unroll
  for (int d=1; d<16; d<<=1){
#pragma unroll
    for (int r2=0; r2<4; r2++){
      sv[r2] += __shfl_xor(sv[r2], d);
      sq[r2] += __shfl_xor(sq[r2], d);
    }
  }
  float* red = (float*)(smb + 32768);   // 64 rows x {s0,q0,s1,q1}
  if (lr16 == 0){
#pragma unroll
    for (int r2=0; r2<4; r2++){
      int row = wr*16 + lg*4 + r2;
      red[row*4 + wc*2]     = sv[r2];
      red[row*4 + wc*2 + 1] = sq[r2];
    }
  }
  __syncthreads();
  float gg[6], be[6];
#pragma unroll
  for (int nt=0; nt<6; nt++){
    int col = wc*96 + nt*16 + lr16;
    gg[nt] = lng[col]; be[nt] = lnb[col];
  }
#pragma unroll
  for (int r2=0; r2<4; r2++){
    int row = wr*16 + lg*4 + r2;
    float s = red[row*4] + red[row*4+2];
    float q = red[row*4+1] + red[row*4+3];
    float mean = s*(1.f/192.f);
    float var  = fmaxf(q*(1.f/192.f) - mean*mean, 0.f);
    float rstd = rsqrtf(var + 1e-5f);
#pragma unroll
    for (int nt=0; nt<6; nt++){
      int col = wc*96 + nt*16 + lr16;
      size_t idx = (size_t)(m0 + row)*192 + col;
      float r = (acc[nt][r2] - mean)*rstd*gg[nt] + be[nt] + base32[idx];
      out16[idx] = f2bf(r);
    }
  }
}

// ------- windowed cosine attention, all-register P, 6 heads per block --------
__global__ __launch_bounds__(384) void attn_kernel(
    const u16* __restrict__ qkv, const float* __restrict__ lsc,
    const float* __restrict__ biasQ, u16* __restrict__ attn_out)
{
  __shared__ __align__(16) u16 smem[12288];  // 6 x 4KB head regions
  const int tid  = threadIdx.x;
  const int wave = tid >> 6;
  const int lane = tid & 63;
  char* smb = (char*)smem + wave*4096;
  const int hh = wave;
  const int w  = blockIdx.x;
  const int b  = w >> 8;
  const int wh = (w >> 4) & 15, ww = w & 15;
  const int lg = lane >> 4, lr = lane & 15;
  const int type = ((wh==15)?2:0) + ((ww==15)?1:0);
  const float qscale = __expf(fminf(lsc[hh], LOG100_)) * LOG2E_;

  union BU { bf16x8 v; u32 u[4]; };

  const int myrow = rowelem(b, wh, ww, min(lane, 48));

  const u16* vsrc = qkv + (size_t)myrow*QKVN_ + 384 + hh*32;
  uint4 vld[4];
#pragma unroll
  for (int r=0; r<4; r++) vld[r] = *(const uint4*)(vsrc + r*8);

  int rowq[4], krow[4];
#pragma unroll
  for (int qt=0; qt<4; qt++) rowq[qt] = __shfl(myrow, qt*16 + lr);
#pragma unroll
  for (int kt=0; kt<4; kt++){
    int sig = ((kt>>1)<<5) + ((lr>>2)<<3) + ((kt&1)<<2) + (lr&3);
    krow[kt] = __shfl(myrow, sig);
  }

  bf16x8 qf[4], kf[4];
#pragma unroll
  for (int qt=0; qt<4; qt++){
    const u16* base = qkv + (size_t)rowq[qt]*QKVN_ + hh*32 + lg*8;
    uint4 u = *(const uint4*)base;
    float f[8]; u4_to_f8(u, f);
    float ss = 0.f;
#pragma unroll
    for (int d=0; d<8; d++) ss += f[d]*f[d];
    ss += __shfl_xor(ss, 16); ss += __shfl_xor(ss, 32);
    float rn = qscale * __builtin_amdgcn_rcpf(fmaxf(sqrtf(ss), 1e-6f));
    BU bu;
#pragma unroll
    for (int p=0; p<4; p++) bu.u[p] = cvtpk(f[2*p]*rn, f[2*p+1]*rn);
    qf[qt] = bu.v;
  }
#pragma unroll
  for (int kt=0; kt<4; kt++){
    const u16* base = qkv + (size_t)krow[kt]*QKVN_ + 192 + hh*32 + lg*8;
    uint4 u = *(const uint4*)base;
    float f[8]; u4_to_f8(u, f);
    float ss = 0.f;
#pragma unroll
    for (int d=0; d<8; d++) ss += f[d]*f[d];
    ss += __shfl_xor(ss, 16); ss += __shfl_xor(ss, 32);
    float rn = __builtin_amdgcn_rcpf(fmaxf(sqrtf(ss), 1e-6f));
    BU bu;
#pragma unroll
    for (int p=0; p<4; p++) bu.u[p] = cvtpk(f[2*p]*rn, f[2*p+1]*rn);
    kf[kt] = bu.v;
  }

  f32x4 s2[4][4];
#pragma unroll
  for (int kt=0; kt<4; kt++)
#pragma unroll
    for (int qt=0; qt<4; qt++)
      s2[kt][qt] = __builtin_amdgcn_mfma_f32_16x16x32_bf16(kf[kt], qf[qt],
                     (f32x4){0.f,0.f,0.f,0.f}, 0, 0, 0);

#pragma unroll
  for (int r=0; r<4; r++){
    u32 wds[4] = {vld[r].x, vld[r].y, vld[r].z, vld[r].w};
#pragma unroll
    for (int i=0; i<8; i++){
      int d = r*8 + i;
      u16 val = (u16)(wds[i>>1] >> ((i&1)*16));
      int addr = (d*128 + lane*2) ^ ((d&7)<<4);
      *(u16*)(smb + addr) = val;
    }
  }

  const float* bq = biasQ + (size_t)(type*6 + hh)*4096;
#pragma unroll
  for (int qt=0; qt<4; qt++){
    int q = qt*16 + lr;
#pragma unroll
    for (int kt=0; kt<4; kt++){
      f32x4 bv = *(const f32x4*)(bq + q*64 + kt*16 + lg*4);
      s2[kt][qt] += bv;
    }
  }
#pragma unroll
  for (int qt=0; qt<4; qt++){
    float m = s2[0][qt][0];
#pragma unroll
    for (int kt=0; kt<4; kt++)
#pragma unroll
      for (int r2=0; r2<4; r2++) m = fmaxf(m, s2[kt][qt][r2]);
    m = fmaxf(m, __shfl_xor(m, 16));
    m = fmaxf(m, __shfl_xor(m, 32));
    float sum = 0.f;
#pragma unroll
    for (int kt=0; kt<4; kt++)
#pragma unroll
      for (int r2=0; r2<4; r2++){
        float e = exp2f(s2[kt][qt][r2] - m);
        s2[kt][qt][r2] = e; sum += e;
      }
    sum += __shfl_xor(sum, 16);
    sum += __shfl_xor(sum, 32);
    float rs = __builtin_amdgcn_rcpf(sum);
#pragma unroll
    for (int kt=0; kt<4; kt++)
#pragma unroll
      for (int r2=0; r2<4; r2++) s2[kt][qt][r2] *= rs;
  }

  __syncthreads();   // V^T ready

  f32x4 o2[2][4];
#pragma unroll
  for (int dt=0; dt<2; dt++)
#pragma unroll
    for (int qt=0; qt<4; qt++)
      o2[dt][qt] = (f32x4){0.f,0.f,0.f,0.f};

#pragma unroll
  for (int kb=0; kb<2; kb++){
    bf16x8 af[2];
#pragma unroll
    for (int dt=0; dt<2; dt++){
      int d = dt*16 + lr;
      int addr = (d*128 + kb*64 + lg*16) ^ ((d&7)<<4);
      af[dt] = *(const bf16x8*)(smb + addr);
    }
#pragma unroll
    for (int qt=0; qt<4; qt++){
      BU bu;
      bu.u[0] = cvtpk(s2[2*kb][qt][0],   s2[2*kb][qt][1]);
      bu.u[1] = cvtpk(s2[2*kb][qt][2],   s2[2*kb][qt][3]);
      bu.u[2] = cvtpk(s2[2*kb+1][qt][0], s2[2*kb+1][qt][1]);
      bu.u[3] = cvtpk(s2[2*kb+1][qt][2], s2[2*kb+1][qt][3]);
#pragma unroll
      for (int dt=0; dt<2; dt++)
        o2[dt][qt] = __builtin_amdgcn_mfma_f32_16x16x32_bf16(af[dt], bu.v, o2[dt][qt], 0, 0, 0);
    }
  }

#pragma unroll
  for (int qt=0; qt<4; qt++){
    int q = qt*16 + lr;
    if (q < 49){
      u16* op = attn_out + (size_t)rowq[qt]*C_ + hh*32;
#pragma unroll
      for (int dt=0; dt<2; dt++){
        uint2 u2;
        u2.x = cvtpk(o2[dt][qt][0], o2[dt][qt][1]);
        u2.y = cvtpk(o2[dt][qt][2], o2[dt][qt][3]);
        *(uint2*)(void*)(op + dt*16 + lg*4) = u2;
      }
    }
  }
}

// ---------------- fused MLP v3: out = h1 + LN2(gelu(h1@W1+b1)@W2+b2) ---------
// 64 rows/block, 512 thr = 8 waves of 16x96 (measured-best, R12/R14/R16).
__global__ __launch_bounds__(512,4) void mlp_fused_kernel(
    const u16* __restrict__ h1,           // [M][192] bf16
    const u16* __restrict__ wf1,          // [768][192] bf16
    const float* __restrict__ bf1,        // [768]
    const u16* __restrict__ wf2,          // [192][768] bf16
    const float* __restrict__ bf2,        // [192]
    const float* __restrict__ lng, const float* __restrict__ lnb,
    float* __restrict__ out)              // [M][192] f32
{
  __shared__ __align__(16) char smb[75776];
  const int tid  = threadIdx.x;
  const int wave = tid >> 6, lane = tid & 63;
  const int m0 = blockIdx.x * 64;
  const int wr = wave >> 1, wc = wave & 1;     // wave tile 16 rows x 96 cols
  const int lr16 = lane & 15, lg = lane >> 4;
  const int lrow = lane >> 2, lslot = lane & 3;
  const int gko = (lslot ^ ((lrow >> 1) & 3)) * 8;
  const int slot8 = (lg ^ ((lr16 >> 1) & 3)) * 8;

  {
    const u16* src = h1 + (size_t)m0*192;
#pragma unroll
    for (int j=0; j<3; j++){
      int i = tid + 512*j;
      int row = i/24, c8 = i%24;
      uint4 v = *(const uint4*)(src + i*8);
      *(uint4*)(smb + row*400 + c8*16) = v;
    }
  }

#define STG1(c_, k_, ph_) do { \
  _Pragma("unroll") \
  for (int s_=0; s_<2; s_++){ \
    int ch__ = wave + s_*8; \
    if (ch__ < 12){ \
      const u16* sp__ = wf1 + (size_t)((c_)*192 + ch__*16 + lrow)*192 + (k_)*32 + gko; \
      __builtin_amdgcn_global_load_lds( \
          (const __attribute__((address_space(1))) void*)sp__, \
          (__attribute__((address_space(3))) void*)(smb + (ph_) + ch__*1024), 16, 0, 0); \
    } } } while(0)
#define STG2(c_, k_, ph_) do { \
  _Pragma("unroll") \
  for (int s_=0; s_<2; s_++){ \
    int ch__ = wave + s_*8; \
    if (ch__ < 12){ \
      const u16* sp__ = wf2 + (size_t)(ch__*16 + lrow)*768 + (c_)*192 + (k_)*32 + gko; \
      __builtin_amdgcn_global_load_lds( \
          (const __attribute__((address_space(1))) void*)sp__, \
          (__attribute__((address_space(3))) void*)(smb + (ph_) + ch__*1024), 16, 0, 0); \
    } } } while(0)

  f32x4 oacc[6];
#pragma unroll
  for (int nt=0; nt<6; nt++) oacc[nt] = (f32x4){0.f,0.f,0.f,0.f};

  for (int c=0; c<4; c++){
    f32x4 macc[6];
#pragma unroll
    for (int nt=0; nt<6; nt++) macc[nt] = (f32x4){0.f,0.f,0.f,0.f};

    STG1(c, 0, 51200u);
    __syncthreads();
#pragma unroll
    for (int k=0; k<6; k++){
      u32 pb = 51200u + (u32)(k&1)*12288u;
      if (k < 5) STG1(c, k+1, 51200u + (u32)((k+1)&1)*12288u);
      bf16x8 af = *(const bf16x8*)(smb + ((wr*16 + lr16)*200 + k*32 + lg*8)*2);
      bf16x8 bfv[6];
#pragma unroll
      for (int nt=0; nt<6; nt++)
        bfv[nt] = *(const bf16x8*)(smb + pb + ((wc*96 + nt*16 + lr16)*32 + slot8)*2);
#pragma unroll
      for (int nt=0; nt<6; nt++)
        macc[nt] = __builtin_amdgcn_mfma_f32_16x16x32_bf16(af, bfv[nt], macc[nt], 0, 0, 0);
      __syncthreads();
    }
    STG2(c, 0, 51200u);
#pragma unroll
    for (int nt=0; nt<6; nt++){
      int col = wc*96 + nt*16 + lr16;
      float bsv = bf1[c*192 + col];
#pragma unroll
      for (int r2=0; r2<4; r2++){
        int tok = wr*16 + lg*4 + r2;
        float g = fast_gelu(macc[nt][r2] + bsv);
        *(u16*)(smb + 25600 + (tok*200 + col)*2) = f2bf(g);
      }
    }
    __syncthreads();
#pragma unroll
    for (int k=0; k<6; k++){
      u32 pb = 51200u + (u32)(k&1)*12288u;
      if (k < 5) STG2(c, k+1, 51200u + (u32)((k+1)&1)*12288u);
      bf16x8 af = *(const bf16x8*)(smb + 25600 + ((wr*16 + lr16)*200 + k*32 + lg*8)*2);
      bf16x8 bfv[6];
#pragma unroll
      for (int nt=0; nt<6; nt++)
        bfv[nt] = *(const bf16x8*)(smb + pb + ((wc*96 + nt*16 + lr16)*32 + slot8)*2);
#pragma unroll
      for (int nt=0; nt<6; nt++)
        oacc[nt] = __builtin_amdgcn_mfma_f32_16x16x32_bf16(af, bfv[nt], oacc[nt], 0, 0, 0);
      __syncthreads();
    }
  }
#undef STG1
#undef STG2

#pragma unroll
  for (int nt=0; nt<6; nt++){
    float bsv = bf2[wc*96 + nt*16 + lr16];
#pragma unroll
    for (int r2=0; r2<4; r2++) oacc[nt][r2] += bsv;
  }
  float sv[4], sq[4];
#pragma unroll
  for (int r2=0; r2<4; r2++){
    float s=0.f, q=0.f;
#pragma unroll
    for (int nt=0; nt<6; nt++){ float x = oacc[nt][r2]; s += x; q += x*x; }
    sv[r2]=s; sq[r2]=q;
  }
#pragma unroll
  for (int d=1; d<16; d<<=1){
#pragma unroll
    for (int r2=0; r2<4; r2++){
      sv[r2] += __shfl_xor(sv[r2], d);
      sq[r2] += __shfl_xor(sq[r2], d);
    }
  }
  float* red = (float*)(smb + 51200);
  if (lr16 == 0){
#pragma unroll
    for (int r2=0; r2<4; r2++){
      int row = wr*16 + lg*4 + r2;
      red[row*4 + wc*2]     = sv[r2];
      red[row*4 + wc*2 + 1] = sq[r2];
    }
  }
  __syncthreads();
  float gg[6], be[6];
#pragma unroll
  for (int nt=0; nt<6; nt++){
    int col = wc*96 + nt*16 + lr16;
    gg[nt] = lng[col]; be[nt] = lnb[col];
  }
#pragma unroll
  for (int r2=0; r2<4; r2++){
    int row = wr*16 + lg*4 + r2;
    float s = red[row*4] + red[row*4+2];
    float q = red[row*4+1] + red[row*4+3];
    float mean = s*(1.f/192.f);
    float var  = fmaxf(q*(1.f/192.f) - mean*mean, 0.f);
    float rstd = rsqrtf(var + 1e-5f);
#pragma unroll
    for (int nt=0; nt<6; nt++){
      int col = wc*96 + nt*16 + lr16;
      float base = bf2f(*(const u16*)(smb + (row*200 + col)*2));
      out[(size_t)(m0 + row)*192 + col] = base + (oacc[nt][r2] - mean)*rstd*gg[nt] + be[nt];
    }
  }
}

// ---------------- launch ------------------------------------------------------
extern "C" void kernel_launch(void* const* d_in, const int* in_sizes, int n_in,
                              void* d_out, int out_size, void* d_ws, size_t ws_size,
                              hipStream_t stream)
{
  (void)in_sizes; (void)n_in; (void)out_size; (void)ws_size;
  const float* x      = (const float*)d_in[0];
  const float* q_w    = (const float*)d_in[1];
  const float* q_b    = (const float*)d_in[2];
  const float* k_w    = (const float*)d_in[3];
  const float* v_w    = (const float*)d_in[4];
  const float* v_b    = (const float*)d_in[5];
  const float* proj_w = (const float*)d_in[6];
  const float* proj_b = (const float*)d_in[7];
  const float* lsc    = (const float*)d_in[8];
  const float* cpb_w0 = (const float*)d_in[9];
  const float* cpb_b0 = (const float*)d_in[10];
  const float* cpb_w1 = (const float*)d_in[11];
  const float* ln1_g  = (const float*)d_in[12];
  const float* ln1_b  = (const float*)d_in[13];
  const float* ln2_g  = (const float*)d_in[14];
  const float* ln2_b  = (const float*)d_in[15];
  const float* fc1_w  = (const float*)d_in[16];
  const float* fc1_b  = (const float*)d_in[17];
  const float* fc2_w  = (const float*)d_in[18];
  const float* fc2_b  = (const float*)d_in[19];

  char* ws = (char*)d_ws;
  size_t o = 0;
  u16* qkvb = (u16*)(ws + o);    o += 154140672;
  u16* attn_o = (u16*)(ws + o);
  u16* h1b    = attn_o;          o += 38535168;    // attn_o -> h1b (in-place fused)
  u16* wt_qkv = (u16*)(ws + o);  o += 221184;
  float* b_qkv= (float*)(ws + o);o += 2304;
  u16* wt_p   = (u16*)(ws + o);  o += 73728;
  float* b_p  = (float*)(ws + o);o += 768;
  u16* wt_f1  = (u16*)(ws + o);  o += 294912;
  float* b_f1 = (float*)(ws + o);o += 3072;
  u16* wt_f2  = (u16*)(ws + o);  o += 294912;
  float* b_f2 = (float*)(ws + o);o += 768;
  float* rpb169 = (float*)(ws + o); o += 4096;
  float* biasQ  = (float*)(ws + o); o += 393216;

  prep_weights<<<1735, 256, 0, stream>>>(q_w, q_b, k_w, v_w, v_b, proj_w, proj_b,
      fc1_w, fc1_b, fc2_w, fc2_b, wt_qkv, b_qkv, wt_p, b_p, wt_f1, b_f1, wt_f2, b_f2);
  rpb_a_kernel<<<169, 64, 0, stream>>>(cpb_w0, cpb_b0, cpb_w1, rpb169);
  rpb_b_kernel<<<384, 256, 0, stream>>>(rpb169, biasQ);

  gemm_qkv_kernel<<<dim3(1568,3), 512, 0, stream>>>(x, wt_qkv, b_qkv, qkvb);
  attn_kernel<<<2048, 384, 0, stream>>>(qkvb, lsc, biasQ, attn_o);
  // h1b = x + LN1(attn_o @ wp + bp)
  proj_ln1_kernel<<<1568, 512, 0, stream>>>(
      attn_o, wt_p, b_p, ln1_g, ln1_b, x, h1b);
  // out = h1b + LN2(gelu(h1b@wf1+b1)@wf2+b2)
  mlp_fused_kernel<<<1568, 512, 0, stream>>>(
      h1b, wt_f1, b_f1, wt_f2, b_f2, ln2_g, ln2_b, (float*)d_out);
}